// Round 1
// baseline (8279.049 us; speedup 1.0000x reference)
//
#include <hip/hip_runtime.h>
#include <math.h>

#define EPSV 1e-8f

constexpr int BB = 128;   // batch
constexpr int LL = 512;   // text words
constexpr int RR = 512;   // image regions
constexpr int DT = 300;   // text embed
constexpr int DI = 1024;  // image embed
constexpr int DD = 256;   // joint dim
constexpr float LSM = 9.0f;   // softmax temperature
constexpr float SLOPE = 0.1f; // leaky relu

// ---------------------------------------------------------------------------
// Projection + bias + L2-normalize.  Y[m][t] = l2norm(X[m]·W[:,t] + b[t])
// One block = MT rows x 256 cols (t = threadIdx.x owns one output column).
// Row chunks staged in LDS; W streamed (L2-resident) with MT-way reuse.
// ---------------------------------------------------------------------------
template <int MT, int KE>
__global__ __launch_bounds__(256) void proj_l2norm(
    const float* __restrict__ X, const float* __restrict__ W,
    const float* __restrict__ bias, float* __restrict__ Y, int E) {
  __shared__ float xs[MT][KE];
  __shared__ float red[MT][4];

  const int t = threadIdx.x;
  const int r0 = blockIdx.x * MT;

  float acc[MT];
#pragma unroll
  for (int m = 0; m < MT; ++m) acc[m] = 0.f;

  for (int e0 = 0; e0 < E; e0 += KE) {
    const int ke = min(KE, E - e0);
    __syncthreads();  // protect xs from previous chunk's readers
    for (int idx = t; idx < MT * KE; idx += 256) {
      const int m = idx / KE, e = idx % KE;
      xs[m][e] = (e < ke) ? X[(size_t)(r0 + m) * E + e0 + e] : 0.f;
    }
    __syncthreads();
    for (int e = 0; e < ke; e += 4) {  // E is a multiple of 4 (300, 1024)
      const float w0 = W[(size_t)(e0 + e) * DD + t];
      const float w1 = W[(size_t)(e0 + e + 1) * DD + t];
      const float w2 = W[(size_t)(e0 + e + 2) * DD + t];
      const float w3 = W[(size_t)(e0 + e + 3) * DD + t];
#pragma unroll
      for (int m = 0; m < MT; ++m) {
        const float4 x = *reinterpret_cast<const float4*>(&xs[m][e]);
        acc[m] = fmaf(x.x, w0, acc[m]);
        acc[m] = fmaf(x.y, w1, acc[m]);
        acc[m] = fmaf(x.z, w2, acc[m]);
        acc[m] = fmaf(x.w, w3, acc[m]);
      }
    }
  }

  const float bv = bias[t];
#pragma unroll
  for (int m = 0; m < MT; ++m) acc[m] += bv;

  const int lane = t & 63, wid = t >> 6;
#pragma unroll
  for (int m = 0; m < MT; ++m) {
    float s = acc[m] * acc[m];
#pragma unroll
    for (int off = 32; off > 0; off >>= 1) s += __shfl_down(s, off, 64);
    if (lane == 0) red[m][wid] = s;
  }
  __syncthreads();
#pragma unroll
  for (int m = 0; m < MT; ++m) {
    const float n2 = red[m][0] + red[m][1] + red[m][2] + red[m][3];
    const float inv = 1.f / (sqrtf(n2) + EPSV);
    Y[(size_t)(r0 + m) * DD + t] = acc[m] * inv;
  }
}

// ---------------------------------------------------------------------------
// One direction of cross attention + cosine relevance, flash-style.
//   For each query row q (of 512 per batch): scores over 512 KV rows,
//   p = exp(9*leaky(dot) - 9)   (dot in [-1,1] so max-shift of 9 is exact),
//   O = sum p*KV / sum p,  cos(Qrow, O), block-sum -> atomicAdd(out[b]).
// Block = (batch b, 16-query tile), 256 threads.
// ---------------------------------------------------------------------------
constexpr int QT = 16;  // queries per block
constexpr int RC = 16;  // kv rows per chunk
constexpr int NROW = 512;

__global__ __launch_bounds__(256) void cross_attn(
    const float* __restrict__ Q, const float* __restrict__ KV,
    float* __restrict__ out, float invN) {
  __shared__ float qt[QT][DD + 4];   // +4 pad: conflict-free b128 broadcast
  __shared__ float P[QT][RC + 4];    // +4 pad keeps rows 16B-aligned
  __shared__ float ssum[QT];
  __shared__ float red[QT][4][3];
  __shared__ float cpart[QT];

  const int t = threadIdx.x;
  const int b = blockIdx.y;
  const int q0 = blockIdx.x * QT;
  const size_t qbase = ((size_t)b * NROW + q0) * DD;
  const size_t kbase = (size_t)b * NROW * DD;

  for (int idx = t; idx < QT * DD; idx += 256) {
    const int m = idx >> 8, d = idx & 255;
    qt[m][d] = Q[qbase + (size_t)m * DD + d];
  }
  if (t < QT) ssum[t] = 0.f;

  const int q = t >> 4, rt = t & 15;
  float accO[QT];
#pragma unroll
  for (int m = 0; m < QT; ++m) accO[m] = 0.f;
  __syncthreads();

  for (int rc = 0; rc < NROW; rc += RC) {
    // ---- scores: thread (q, rt) computes dot(qt[q], KV[rc+rt]) ----
    const float* kv = &KV[kbase + (size_t)(rc + rt) * DD];
    float dot = 0.f;
#pragma unroll 8
    for (int d4 = 0; d4 < DD; d4 += 4) {
      const float4 qv = *reinterpret_cast<const float4*>(&qt[q][d4]);
      const float4 kk = *reinterpret_cast<const float4*>(&kv[d4]);
      dot = fmaf(qv.x, kk.x, dot);
      dot = fmaf(qv.y, kk.y, dot);
      dot = fmaf(qv.z, kk.z, dot);
      dot = fmaf(qv.w, kk.w, dot);
    }
    const float a = (dot > 0.f) ? dot : SLOPE * dot;
    P[q][rt] = __expf(LSM * a - LSM);
    __syncthreads();

    if (t < QT) {  // denominator accumulation (thread t handles query t)
      float s = 0.f;
#pragma unroll
      for (int r = 0; r < RC; ++r) s += P[t][r];
      ssum[t] += s;
    }

    // ---- PV: thread t owns output column t for all 16 queries ----
    float iv[RC];
#pragma unroll
    for (int r = 0; r < RC; ++r) iv[r] = KV[kbase + (size_t)(rc + r) * DD + t];
#pragma unroll
    for (int m = 0; m < QT; ++m) {
      const float4 p0 = *reinterpret_cast<const float4*>(&P[m][0]);
      const float4 p1 = *reinterpret_cast<const float4*>(&P[m][4]);
      const float4 p2 = *reinterpret_cast<const float4*>(&P[m][8]);
      const float4 p3 = *reinterpret_cast<const float4*>(&P[m][12]);
      float o = accO[m];
      o = fmaf(p0.x, iv[0], o);  o = fmaf(p0.y, iv[1], o);
      o = fmaf(p0.z, iv[2], o);  o = fmaf(p0.w, iv[3], o);
      o = fmaf(p1.x, iv[4], o);  o = fmaf(p1.y, iv[5], o);
      o = fmaf(p1.z, iv[6], o);  o = fmaf(p1.w, iv[7], o);
      o = fmaf(p2.x, iv[8], o);  o = fmaf(p2.y, iv[9], o);
      o = fmaf(p2.z, iv[10], o); o = fmaf(p2.w, iv[11], o);
      o = fmaf(p3.x, iv[12], o); o = fmaf(p3.y, iv[13], o);
      o = fmaf(p3.z, iv[14], o); o = fmaf(p3.w, iv[15], o);
      accO[m] = o;
    }
    __syncthreads();  // P consumed; safe to overwrite next chunk
  }

  // ---- cosine epilogue ----
  const int lane = t & 63, wid = t >> 6;
#pragma unroll
  for (int m = 0; m < QT; ++m) {
    const float Od = accO[m] / ssum[m];
    const float qv = qt[m][t];
    float dp = qv * Od, o2 = Od * Od, q2 = qv * qv;
#pragma unroll
    for (int off = 32; off > 0; off >>= 1) {
      dp += __shfl_down(dp, off, 64);
      o2 += __shfl_down(o2, off, 64);
      q2 += __shfl_down(q2, off, 64);
    }
    if (lane == 0) { red[m][wid][0] = dp; red[m][wid][1] = o2; red[m][wid][2] = q2; }
  }
  __syncthreads();
  if (t < QT) {
    const float dp = red[t][0][0] + red[t][1][0] + red[t][2][0] + red[t][3][0];
    const float o2 = red[t][0][1] + red[t][1][1] + red[t][2][1] + red[t][3][1];
    const float q2 = red[t][0][2] + red[t][1][2] + red[t][2][2] + red[t][3][2];
    cpart[t] = dp / (sqrtf(q2) * sqrtf(o2) + EPSV) * invN;
  }
  __syncthreads();
  if (t == 0) {
    float s = 0.f;
#pragma unroll
    for (int m = 0; m < QT; ++m) s += cpart[m];
    atomicAdd(&out[b], s);
  }
}

// ---------------------------------------------------------------------------
extern "C" void kernel_launch(void* const* d_in, const int* in_sizes, int n_in,
                              void* d_out, int out_size, void* d_ws, size_t ws_size,
                              hipStream_t stream) {
  const float* text  = (const float*)d_in[0];
  const float* image = (const float*)d_in[1];
  const float* Wt    = (const float*)d_in[2];
  const float* bt    = (const float*)d_in[3];
  const float* Wi    = (const float*)d_in[4];
  const float* bi    = (const float*)d_in[5];
  float* out = (float*)d_out;

  float* tf  = (float*)d_ws;                       // 128*512*256 f32 = 67 MB
  float* imf = tf + (size_t)BB * LL * DD;          // 67 MB

  hipMemsetAsync(out, 0, sizeof(float) * BB, stream);

  proj_l2norm<16, 128><<<dim3((BB * LL) / 16), 256, 0, stream>>>(text, Wt, bt, tf, DT);
  proj_l2norm<16, 128><<<dim3((BB * RR) / 16), 256, 0, stream>>>(image, Wi, bi, imf, DI);

  // text-to-image: words attend over regions; cosine(tf, image_ss), mean over L
  cross_attn<<<dim3(LL / QT, BB), 256, 0, stream>>>(tf, imf, out, 1.0f / LL);
  // image-to-text: regions attend over words; cosine(text_ss, imf), mean over R
  cross_attn<<<dim3(RR / QT, BB), 256, 0, stream>>>(imf, tf, out, 1.0f / RR);
}

// Round 2
// 1143.412 us; speedup vs baseline: 7.2407x; 7.2407x over previous
//
#include <hip/hip_runtime.h>
#include <math.h>

#define EPSV 1e-8f

constexpr int BB = 128;   // batch
constexpr int NROW = 512; // words = regions = 512
constexpr int DT = 300;   // text embed
constexpr int DI = 1024;  // image embed
constexpr int DD = 256;   // joint dim

typedef __bf16 bf16x8 __attribute__((ext_vector_type(8)));
typedef float f32x4 __attribute__((ext_vector_type(4)));

__device__ inline unsigned short f2bf(float f) {
  unsigned int x = __builtin_bit_cast(unsigned int, f);
  unsigned int r = (x + 0x7fffu + ((x >> 16) & 1u)) >> 16;
  return (unsigned short)r;
}
__device__ inline float bf2f(unsigned short u) {
  return __builtin_bit_cast(float, (unsigned int)u << 16);
}

// ---------------------------------------------------------------------------
// Projection + bias + L2-normalize -> bf16 row-major Yb AND bf16 per-batch
// transposed Yt[b][d][row].  One block = 16 rows x 256 cols.
// ---------------------------------------------------------------------------
template <int MT, int KE>
__global__ __launch_bounds__(256) void proj_l2norm(
    const float* __restrict__ X, const float* __restrict__ W,
    const float* __restrict__ bias, unsigned short* __restrict__ Yb,
    unsigned short* __restrict__ Yt, int E) {
  __shared__ float xs[MT][KE];
  __shared__ float red[MT][4];

  const int t = threadIdx.x;
  const int r0 = blockIdx.x * MT;

  float acc[MT];
#pragma unroll
  for (int m = 0; m < MT; ++m) acc[m] = 0.f;

  for (int e0 = 0; e0 < E; e0 += KE) {
    const int ke = min(KE, E - e0);
    __syncthreads();
    for (int idx = t; idx < MT * KE; idx += 256) {
      const int m = idx / KE, e = idx % KE;
      xs[m][e] = (e < ke) ? X[(size_t)(r0 + m) * E + e0 + e] : 0.f;
    }
    __syncthreads();
    for (int e = 0; e < ke; e += 4) {
      const float w0 = W[(size_t)(e0 + e) * DD + t];
      const float w1 = W[(size_t)(e0 + e + 1) * DD + t];
      const float w2 = W[(size_t)(e0 + e + 2) * DD + t];
      const float w3 = W[(size_t)(e0 + e + 3) * DD + t];
#pragma unroll
      for (int m = 0; m < MT; ++m) {
        const float4 x = *reinterpret_cast<const float4*>(&xs[m][e]);
        acc[m] = fmaf(x.x, w0, acc[m]);
        acc[m] = fmaf(x.y, w1, acc[m]);
        acc[m] = fmaf(x.z, w2, acc[m]);
        acc[m] = fmaf(x.w, w3, acc[m]);
      }
    }
  }

  const float bv = bias[t];
#pragma unroll
  for (int m = 0; m < MT; ++m) acc[m] += bv;

  const int lane = t & 63, wid = t >> 6;
#pragma unroll
  for (int m = 0; m < MT; ++m) {
    float s = acc[m] * acc[m];
#pragma unroll
    for (int off = 32; off > 0; off >>= 1) s += __shfl_down(s, off, 64);
    if (lane == 0) red[m][wid] = s;
  }
  __syncthreads();
  unsigned int ys[MT];
#pragma unroll
  for (int m = 0; m < MT; ++m) {
    const float n2 = red[m][0] + red[m][1] + red[m][2] + red[m][3];
    const float inv = 1.f / (sqrtf(n2) + EPSV);
    const unsigned short u = f2bf(acc[m] * inv);
    Yb[(size_t)(r0 + m) * DD + t] = u;
    ys[m] = u;
  }
  // transposed write: Yt[b][t][r0%512 + m], 16 bf16 = 32B contiguous per thread
  const int bb = r0 >> 9;
  const size_t tb = ((size_t)bb * DD + t) * NROW + (r0 & 511);
  uint4 lo, hi;
  lo.x = ys[0] | (ys[1] << 16);  lo.y = ys[2] | (ys[3] << 16);
  lo.z = ys[4] | (ys[5] << 16);  lo.w = ys[6] | (ys[7] << 16);
  hi.x = ys[8] | (ys[9] << 16);  hi.y = ys[10] | (ys[11] << 16);
  hi.z = ys[12] | (ys[13] << 16); hi.w = ys[14] | (ys[15] << 16);
  *reinterpret_cast<uint4*>(&Yt[tb]) = lo;
  *reinterpret_cast<uint4*>(&Yt[tb + 8]) = hi;
}

// ---------------------------------------------------------------------------
// MFMA flash cross-attention + cosine relevance (one direction).
// Block: 256 thr = 4 waves; wave owns 32 queries; block Q-tile = 128.
// KV chunk = 32 rows staged in LDS (K row-major, V transposed), shared by
// all 4 waves.  Swapped QK^T (mfma(K, Q^T)) makes P lane-local in kv.
// ---------------------------------------------------------------------------
__global__ __launch_bounds__(256, 2) void cross_attn_mfma(
    const unsigned short* __restrict__ Qg,   // [b][row][256] bf16 (queries)
    const unsigned short* __restrict__ Kg,   // [b][row][256] bf16 (KV rm)
    const unsigned short* __restrict__ Vtg,  // [b][256][row] bf16 (KV transposed)
    float* __restrict__ out, float invN) {
  __shared__ __align__(16) unsigned short K_lds[32 * 264];    // pad 256+8
  __shared__ __align__(16) unsigned short Vt_lds[256 * 40];   // pad 32+8
  __shared__ __align__(16) unsigned short P_lds[4][32 * 40];  // per-wave

  const int t = threadIdx.x;
  const int l = t & 63;
  const int w = t >> 6;
  const int h = l >> 4;      // 4-lane-group row block
  const int q15 = l & 15;
  const int b = blockIdx.y;
  const int qbase = blockIdx.x * 128 + w * 32;
  const size_t qrow0 = (size_t)b * NROW + qbase;
  const size_t kband = (size_t)b * NROW * DD;  // Kg batch base
  const size_t vband = (size_t)b * DD * NROW;  // Vtg batch base

  // Q fragments (also the B-operand of swapped QK^T): lane l holds
  // Q[qt*16 + (l&15)][kc*32 + h*8 + j], j=0..7
  bf16x8 qf[2][8];
#pragma unroll
  for (int qt = 0; qt < 2; ++qt)
#pragma unroll
    for (int kc = 0; kc < 8; ++kc)
      qf[qt][kc] = *reinterpret_cast<const bf16x8*>(
          &Qg[(qrow0 + qt * 16 + q15) * DD + kc * 32 + h * 8]);

  f32x4 accO[2][16];
#pragma unroll
  for (int qt = 0; qt < 2; ++qt)
#pragma unroll
    for (int nt = 0; nt < 16; ++nt) accO[qt][nt] = (f32x4){0.f, 0.f, 0.f, 0.f};
  float denom[2] = {0.f, 0.f};

  for (int c0 = 0; c0 < NROW; c0 += 32) {
    __syncthreads();  // all waves done reading previous chunk
    // stage K chunk: 32 rows x 256, row stride 264
#pragma unroll
    for (int i = 0; i < 4; ++i) {
      const int slot = t + i * 256;
      const int row = slot >> 5, cc = slot & 31;
      const uint4 v = *reinterpret_cast<const uint4*>(
          &Kg[kband + (size_t)(c0 + row) * DD + cc * 8]);
      *reinterpret_cast<uint4*>(&K_lds[row * 264 + cc * 8]) = v;
    }
    // stage Vt chunk: 256 rows x 32, row stride 40
#pragma unroll
    for (int i = 0; i < 4; ++i) {
      const int slot = t + i * 256;
      const int d = slot >> 2, cc = slot & 3;
      const uint4 v = *reinterpret_cast<const uint4*>(
          &Vtg[vband + (size_t)d * NROW + c0 + cc * 8]);
      *reinterpret_cast<uint4*>(&Vt_lds[d * 40 + cc * 8]) = v;
    }
    __syncthreads();

    // ---- swapped QK^T: S^T[kv][q] ; lane holds S[q=qt*16+q15][kv=kvt*16+4h+r]
    f32x4 accS[2][2];
#pragma unroll
    for (int qt = 0; qt < 2; ++qt)
#pragma unroll
      for (int kvt = 0; kvt < 2; ++kvt) accS[qt][kvt] = (f32x4){0.f, 0.f, 0.f, 0.f};
#pragma unroll
    for (int kc = 0; kc < 8; ++kc) {
#pragma unroll
      for (int kvt = 0; kvt < 2; ++kvt) {
        const bf16x8 kf = *reinterpret_cast<const bf16x8*>(
            &K_lds[(kvt * 16 + q15) * 264 + kc * 32 + h * 8]);
#pragma unroll
        for (int qt = 0; qt < 2; ++qt)
          accS[qt][kvt] = __builtin_amdgcn_mfma_f32_16x16x32_bf16(
              kf, qf[qt][kc], accS[qt][kvt], 0, 0, 0);
      }
    }

    // ---- leaky + exp(9a-9) (exact: scores bounded by ~1); P -> LDS bf16
#pragma unroll
    for (int qt = 0; qt < 2; ++qt) {
#pragma unroll
      for (int kvt = 0; kvt < 2; ++kvt) {
        float p[4];
#pragma unroll
        for (int r = 0; r < 4; ++r) {
          const float s = accS[qt][kvt][r];
          const float a = (s > 0.f) ? s : 0.1f * s;
          p[r] = __expf(9.f * a - 9.f);
          denom[qt] += p[r];
        }
        uint2 pk;
        pk.x = f2bf(p[0]) | ((unsigned)f2bf(p[1]) << 16);
        pk.y = f2bf(p[2]) | ((unsigned)f2bf(p[3]) << 16);
        *reinterpret_cast<uint2*>(
            &P_lds[w][(qt * 16 + q15) * 40 + kvt * 16 + h * 4]) = pk;
      }
    }

    // ---- PV: O[q][d] += P(32q x 32kv) · V(32kv x 256d)
    bf16x8 pf[2];
#pragma unroll
    for (int qt = 0; qt < 2; ++qt)
      pf[qt] = *reinterpret_cast<const bf16x8*>(
          &P_lds[w][(qt * 16 + q15) * 40 + h * 8]);
#pragma unroll
    for (int nt = 0; nt < 16; ++nt) {
      const bf16x8 vf = *reinterpret_cast<const bf16x8*>(
          &Vt_lds[(nt * 16 + q15) * 40 + h * 8]);
#pragma unroll
      for (int qt = 0; qt < 2; ++qt)
        accO[qt][nt] = __builtin_amdgcn_mfma_f32_16x16x32_bf16(
            pf[qt], vf, accO[qt][nt], 0, 0, 0);
    }
  }

  // ---- epilogue: cos(q, O) = dot / (||q||·||O|| + denom*eps), mean, atomic
#pragma unroll
  for (int qt = 0; qt < 2; ++qt) {
    denom[qt] += __shfl_xor(denom[qt], 16, 64);
    denom[qt] += __shfl_xor(denom[qt], 32, 64);
  }
  float total = 0.f;
#pragma unroll
  for (int qt = 0; qt < 2; ++qt) {
#pragma unroll
    for (int r = 0; r < 4; ++r) {
      const int qrow = qt * 16 + h * 4 + r;  // q within wave tile (C-layout row)
      const float dnq = __shfl(denom[qt], h * 4 + r, 64);
      float dot = 0.f, o2 = 0.f, q2 = 0.f;
#pragma unroll
      for (int nt = 0; nt < 16; ++nt) {
        const float ov = accO[qt][nt][r];
        const float qv = bf2f(Qg[(qrow0 + qrow) * DD + nt * 16 + q15]);
        dot = fmaf(ov, qv, dot);
        o2 = fmaf(ov, ov, o2);
        q2 = fmaf(qv, qv, q2);
      }
#pragma unroll
      for (int off = 1; off < 16; off <<= 1) {
        dot += __shfl_xor(dot, off, 64);
        o2 += __shfl_xor(o2, off, 64);
        q2 += __shfl_xor(q2, off, 64);
      }
      total += dot / (sqrtf(o2 * q2) + dnq * EPSV);
    }
  }
  total += __shfl_xor(total, 16, 64);
  total += __shfl_xor(total, 32, 64);
  if (l == 0) atomicAdd(&out[b], invN * total);
}

// ---------------------------------------------------------------------------
extern "C" void kernel_launch(void* const* d_in, const int* in_sizes, int n_in,
                              void* d_out, int out_size, void* d_ws, size_t ws_size,
                              hipStream_t stream) {
  const float* text  = (const float*)d_in[0];
  const float* image = (const float*)d_in[1];
  const float* Wt    = (const float*)d_in[2];
  const float* bt    = (const float*)d_in[3];
  const float* Wi    = (const float*)d_in[4];
  const float* bi    = (const float*)d_in[5];
  float* out = (float*)d_out;

  constexpr size_t NE = (size_t)BB * NROW * DD;  // 16.78M elems per array
  unsigned short* tf   = (unsigned short*)d_ws;  // bf16 row-major
  unsigned short* imf  = tf + NE;
  unsigned short* tft  = imf + NE;               // bf16 [b][d][row]
  unsigned short* imft = tft + NE;

  hipMemsetAsync(out, 0, sizeof(float) * BB, stream);

  proj_l2norm<16, 128><<<dim3((BB * NROW) / 16), 256, 0, stream>>>(
      text, Wt, bt, tf, tft, DT);
  proj_l2norm<16, 128><<<dim3((BB * NROW) / 16), 256, 0, stream>>>(
      image, Wi, bi, imf, imft, DI);

  // text-to-image: words attend over regions; cos(tf, image_ss), mean over L
  cross_attn_mfma<<<dim3(NROW / 128, BB), 256, 0, stream>>>(
      tf, imf, imft, out, 1.0f / NROW);
  // image-to-text: regions attend over words; cos(text_ss, imf), mean over R
  cross_attn_mfma<<<dim3(NROW / 128, BB), 256, 0, stream>>>(
      imf, tf, tft, out, 1.0f / NROW);
}

// Round 4
// 366.104 us; speedup vs baseline: 22.6139x; 3.1232x over previous
//
#include <hip/hip_runtime.h>
#include <math.h>

#define EPSV 1e-8f

constexpr int BB = 128;   // batch
constexpr int NROW = 512; // words = regions = 512
constexpr int DT = 300;   // text embed
constexpr int DI = 1024;  // image embed
constexpr int DD = 256;   // joint dim

typedef __bf16 bf16x8 __attribute__((ext_vector_type(8)));
typedef float f32x4 __attribute__((ext_vector_type(4)));

__device__ inline unsigned short f2bf(float f) {
  unsigned int x = __builtin_bit_cast(unsigned int, f);
  unsigned int r = (x + 0x7fffu + ((x >> 16) & 1u)) >> 16;
  return (unsigned short)r;
}
__device__ inline float bf2f(unsigned short u) {
  return __builtin_bit_cast(float, (unsigned int)u << 16);
}

// ---------------------------------------------------------------------------
// W [E][256] f32  ->  Wt [256][Ep] bf16, zero-padded cols E..Ep.
// ---------------------------------------------------------------------------
__global__ __launch_bounds__(256) void prep_w(
    const float* __restrict__ W, unsigned short* __restrict__ Wt, int E, int Ep) {
  __shared__ float tile[32][36];
  const int t = threadIdx.x;
  const int e0 = blockIdx.x * 32, n0 = blockIdx.y * 32;
  {
    const int r = t >> 3, c4 = (t & 7) * 4;
    float4 v = {0.f, 0.f, 0.f, 0.f};
    if (e0 + r < E) v = *reinterpret_cast<const float4*>(&W[(size_t)(e0 + r) * DD + n0 + c4]);
    tile[r][c4] = v.x; tile[r][c4 + 1] = v.y; tile[r][c4 + 2] = v.z; tile[r][c4 + 3] = v.w;
  }
  __syncthreads();
  {
    const int n = t >> 3, e4 = (t & 7) * 4;
    uint2 pk;
    pk.x = f2bf(tile[e4][n]) | ((unsigned)f2bf(tile[e4 + 1][n]) << 16);
    pk.y = f2bf(tile[e4 + 2][n]) | ((unsigned)f2bf(tile[e4 + 3][n]) << 16);
    *reinterpret_cast<uint2*>(&Wt[(size_t)(n0 + n) * Ep + e0 + e4]) = pk;
  }
}

// ---------------------------------------------------------------------------
// MFMA projection + bias + L2-norm -> bf16 row-major Yb AND transposed Yt.
// 512 thr = 8 waves (2 row x 4 col); block tile 128 rows x 256 cols (full N);
// wave tile 64x64 (4x4 MFMA 16x16x32 accs).  K-chunks of 32 staged in LDS.
// ---------------------------------------------------------------------------
__global__ __launch_bounds__(512, 2) void proj_mfma(
    const float* __restrict__ X, const unsigned short* __restrict__ Wt,
    const float* __restrict__ bias, unsigned short* __restrict__ Yb,
    unsigned short* __restrict__ Yt, int E, int Ep) {
  __shared__ __align__(16) unsigned char smem[65536];
  unsigned short* Xs = (unsigned short*)smem;            // [128][40] bf16 staging
  unsigned short* Ws = (unsigned short*)(smem + 10240);  // [256][40] bf16 staging
  float* red2 = (float*)smem;                            // [128][4]  (after barrier A)
  unsigned short* rp = (unsigned short*)smem;            // [128][256] (after barrier C)

  const int t = threadIdx.x;
  const int l = t & 63, w = t >> 6;
  const int q15 = l & 15, h = l >> 4;
  const int wrow = w >> 2, wcol = w & 3;
  const int row0 = blockIdx.x * 128;

  f32x4 acc[4][4];
#pragma unroll
  for (int rt = 0; rt < 4; ++rt)
#pragma unroll
    for (int ct = 0; ct < 4; ++ct) acc[rt][ct] = (f32x4){0.f, 0.f, 0.f, 0.f};

  const int sxr = t >> 2, sxq = t & 3;  // X staging: row 0..127, col-quad 0..3
  const int swn = t >> 1, swh = t & 1;  // W staging: n 0..255, half 0..1

  for (int e0 = 0; e0 < Ep; e0 += 32) {
    __syncthreads();
    {  // stage X chunk 128x32 f32 -> bf16
      const int eb = e0 + sxq * 8;
      float4 a = {0.f, 0.f, 0.f, 0.f}, b4 = {0.f, 0.f, 0.f, 0.f};
      const float* xp = &X[(size_t)(row0 + sxr) * E + eb];
      if (eb + 4 <= E) a = *reinterpret_cast<const float4*>(xp);
      if (eb + 8 <= E) b4 = *reinterpret_cast<const float4*>(xp + 4);
      uint4 u;
      u.x = f2bf(a.x) | ((unsigned)f2bf(a.y) << 16);
      u.y = f2bf(a.z) | ((unsigned)f2bf(a.w) << 16);
      u.z = f2bf(b4.x) | ((unsigned)f2bf(b4.y) << 16);
      u.w = f2bf(b4.z) | ((unsigned)f2bf(b4.w) << 16);
      *reinterpret_cast<uint4*>(&Xs[sxr * 40 + sxq * 8]) = u;
    }
    {  // stage Wt chunk 256x32 bf16: 2 x uint4 (16 bf16 = 32B) per thread
      const unsigned short* wp = &Wt[(size_t)swn * Ep + e0 + swh * 16];
      const uint4 u0 = *reinterpret_cast<const uint4*>(wp);
      const uint4 u1 = *reinterpret_cast<const uint4*>(wp + 8);
      *reinterpret_cast<uint4*>(&Ws[swn * 40 + swh * 16]) = u0;
      *reinterpret_cast<uint4*>(&Ws[swn * 40 + swh * 16 + 8]) = u1;
    }
    __syncthreads();
    bf16x8 af[4], bfr[4];
#pragma unroll
    for (int rt = 0; rt < 4; ++rt)
      af[rt] = *reinterpret_cast<const bf16x8*>(&Xs[(wrow * 64 + rt * 16 + q15) * 40 + h * 8]);
#pragma unroll
    for (int ct = 0; ct < 4; ++ct)
      bfr[ct] = *reinterpret_cast<const bf16x8*>(&Ws[(wcol * 64 + ct * 16 + q15) * 40 + h * 8]);
#pragma unroll
    for (int rt = 0; rt < 4; ++rt)
#pragma unroll
      for (int ct = 0; ct < 4; ++ct)
        acc[rt][ct] = __builtin_amdgcn_mfma_f32_16x16x32_bf16(af[rt], bfr[ct], acc[rt][ct], 0, 0, 0);
  }

  // ---- epilogue: bias, cross-wave L2 norm, dual-layout bf16 stores ----
  float bias_v[4];
#pragma unroll
  for (int ct = 0; ct < 4; ++ct) bias_v[ct] = bias[wcol * 64 + ct * 16 + q15];
#pragma unroll
  for (int rt = 0; rt < 4; ++rt)
#pragma unroll
    for (int ct = 0; ct < 4; ++ct)
#pragma unroll
      for (int r = 0; r < 4; ++r) acc[rt][ct][r] += bias_v[ct];

  float ss[4][4];
#pragma unroll
  for (int rt = 0; rt < 4; ++rt)
#pragma unroll
    for (int r = 0; r < 4; ++r) {
      float s = 0.f;
#pragma unroll
      for (int ct = 0; ct < 4; ++ct) s = fmaf(acc[rt][ct][r], acc[rt][ct][r], s);
      s += __shfl_xor(s, 1, 64);
      s += __shfl_xor(s, 2, 64);
      s += __shfl_xor(s, 4, 64);
      s += __shfl_xor(s, 8, 64);
      ss[rt][r] = s;
    }

  __syncthreads();  // A: staging LDS dead -> red2 region valid
  if (q15 == 0) {
#pragma unroll
    for (int rt = 0; rt < 4; ++rt)
#pragma unroll
      for (int r = 0; r < 4; ++r)
        red2[(wrow * 64 + rt * 16 + h * 4 + r) * 4 + wcol] = ss[rt][r];
  }
  __syncthreads();  // B
  float inv[4][4];
#pragma unroll
  for (int rt = 0; rt < 4; ++rt)
#pragma unroll
    for (int r = 0; r < 4; ++r) {
      const float4 p = *reinterpret_cast<const float4*>(&red2[(wrow * 64 + rt * 16 + h * 4 + r) * 4]);
      inv[rt][r] = 1.f / (sqrtf(p.x + p.y + p.z + p.w) + EPSV);
    }
  __syncthreads();  // C: red2 dead -> rp region valid

  const int bb = row0 >> 9;
  const int rin0 = row0 & 511;
#pragma unroll
  for (int rt = 0; rt < 4; ++rt) {
#pragma unroll
    for (int ct = 0; ct < 4; ++ct) {
      unsigned short uv[4];
#pragma unroll
      for (int r = 0; r < 4; ++r) uv[r] = f2bf(acc[rt][ct][r] * inv[rt][r]);
      const int col = wcol * 64 + ct * 16 + q15;
#pragma unroll
      for (int r = 0; r < 4; ++r)
        rp[(wrow * 64 + rt * 16 + h * 4 + r) * 256 + col] = uv[r];
      unsigned long long pk = (unsigned long long)uv[0] |
                              ((unsigned long long)uv[1] << 16) |
                              ((unsigned long long)uv[2] << 32) |
                              ((unsigned long long)uv[3] << 48);
      const int rin = rin0 + wrow * 64 + rt * 16 + h * 4;
      *reinterpret_cast<unsigned long long*>(&Yt[((size_t)bb * DD + col) * NROW + rin]) = pk;
    }
  }
  __syncthreads();  // D: rp complete
#pragma unroll
  for (int i = 0; i < 8; ++i) {
    const int s = t + i * 512;
    const int row = s >> 5, c = s & 31;
    const uint4 v = *reinterpret_cast<const uint4*>(&rp[row * 256 + c * 8]);
    *reinterpret_cast<uint4*>(&Yb[(size_t)(row0 + row) * DD + c * 8]) = v;
  }
}

// ---------------------------------------------------------------------------
// MFMA flash cross-attention + cosine relevance (one direction).
// ---------------------------------------------------------------------------
__global__ __launch_bounds__(256, 2) void cross_attn_mfma(
    const unsigned short* __restrict__ Qg,   // [b][row][256] bf16 (queries)
    const unsigned short* __restrict__ Kg,   // [b][row][256] bf16 (KV rm)
    const unsigned short* __restrict__ Vtg,  // [b][256][row] bf16 (KV transposed)
    float* __restrict__ out, float invN) {
  __shared__ __align__(16) unsigned short K_lds[32 * 264];    // pad 256+8
  __shared__ __align__(16) unsigned short Vt_lds[256 * 40];   // pad 32+8
  __shared__ __align__(16) unsigned short P_lds[4][32 * 40];  // per-wave

  const int t = threadIdx.x;
  const int l = t & 63;
  const int w = t >> 6;
  const int h = l >> 4;
  const int q15 = l & 15;
  const int b = blockIdx.y;
  const int qbase = blockIdx.x * 128 + w * 32;
  const size_t qrow0 = (size_t)b * NROW + qbase;
  const size_t kband = (size_t)b * NROW * DD;
  const size_t vband = (size_t)b * DD * NROW;

  bf16x8 qf[2][8];
#pragma unroll
  for (int qt = 0; qt < 2; ++qt)
#pragma unroll
    for (int kc = 0; kc < 8; ++kc)
      qf[qt][kc] = *reinterpret_cast<const bf16x8*>(
          &Qg[(qrow0 + qt * 16 + q15) * DD + kc * 32 + h * 8]);

  f32x4 accO[2][16];
#pragma unroll
  for (int qt = 0; qt < 2; ++qt)
#pragma unroll
    for (int nt = 0; nt < 16; ++nt) accO[qt][nt] = (f32x4){0.f, 0.f, 0.f, 0.f};
  float denom[2] = {0.f, 0.f};

  for (int c0 = 0; c0 < NROW; c0 += 32) {
    __syncthreads();
#pragma unroll
    for (int i = 0; i < 4; ++i) {
      const int slot = t + i * 256;
      const int row = slot >> 5, cc = slot & 31;
      const uint4 v = *reinterpret_cast<const uint4*>(
          &Kg[kband + (size_t)(c0 + row) * DD + cc * 8]);
      *reinterpret_cast<uint4*>(&K_lds[row * 264 + cc * 8]) = v;
    }
#pragma unroll
    for (int i = 0; i < 4; ++i) {
      const int slot = t + i * 256;
      const int d = slot >> 2, cc = slot & 3;
      const uint4 v = *reinterpret_cast<const uint4*>(
          &Vtg[vband + (size_t)d * NROW + c0 + cc * 8]);
      *reinterpret_cast<uint4*>(&Vt_lds[d * 40 + cc * 8]) = v;
    }
    __syncthreads();

    f32x4 accS[2][2];
#pragma unroll
    for (int qt = 0; qt < 2; ++qt)
#pragma unroll
      for (int kvt = 0; kvt < 2; ++kvt) accS[qt][kvt] = (f32x4){0.f, 0.f, 0.f, 0.f};
#pragma unroll
    for (int kc = 0; kc < 8; ++kc) {
#pragma unroll
      for (int kvt = 0; kvt < 2; ++kvt) {
        const bf16x8 kf = *reinterpret_cast<const bf16x8*>(
            &K_lds[(kvt * 16 + q15) * 264 + kc * 32 + h * 8]);
#pragma unroll
        for (int qt = 0; qt < 2; ++qt)
          accS[qt][kvt] = __builtin_amdgcn_mfma_f32_16x16x32_bf16(
              kf, qf[qt][kc], accS[qt][kvt], 0, 0, 0);
      }
    }

#pragma unroll
    for (int qt = 0; qt < 2; ++qt) {
#pragma unroll
      for (int kvt = 0; kvt < 2; ++kvt) {
        float p[4];
#pragma unroll
        for (int r = 0; r < 4; ++r) {
          const float s = accS[qt][kvt][r];
          const float a = (s > 0.f) ? s : 0.1f * s;
          p[r] = __expf(9.f * a - 9.f);
          denom[qt] += p[r];
        }
        uint2 pk;
        pk.x = f2bf(p[0]) | ((unsigned)f2bf(p[1]) << 16);
        pk.y = f2bf(p[2]) | ((unsigned)f2bf(p[3]) << 16);
        *reinterpret_cast<uint2*>(
            &P_lds[w][(qt * 16 + q15) * 40 + kvt * 16 + h * 4]) = pk;
      }
    }

    bf16x8 pf[2];
#pragma unroll
    for (int qt = 0; qt < 2; ++qt)
      pf[qt] = *reinterpret_cast<const bf16x8*>(
          &P_lds[w][(qt * 16 + q15) * 40 + h * 8]);
#pragma unroll
    for (int nt = 0; nt < 16; ++nt) {
      const bf16x8 vf = *reinterpret_cast<const bf16x8*>(
          &Vt_lds[(nt * 16 + q15) * 40 + h * 8]);
#pragma unroll
      for (int qt = 0; qt < 2; ++qt)
        accO[qt][nt] = __builtin_amdgcn_mfma_f32_16x16x32_bf16(
            pf[qt], vf, accO[qt][nt], 0, 0, 0);
    }
  }

#pragma unroll
  for (int qt = 0; qt < 2; ++qt) {
    denom[qt] += __shfl_xor(denom[qt], 16, 64);
    denom[qt] += __shfl_xor(denom[qt], 32, 64);
  }
  float total = 0.f;
#pragma unroll
  for (int qt = 0; qt < 2; ++qt) {
#pragma unroll
    for (int r = 0; r < 4; ++r) {
      const int qrow = qt * 16 + h * 4 + r;
      const float dnq = __shfl(denom[qt], h * 4 + r, 64);
      float dot = 0.f, o2 = 0.f, q2 = 0.f;
#pragma unroll
      for (int nt = 0; nt < 16; ++nt) {
        const float ov = accO[qt][nt][r];
        const float qv = bf2f(Qg[(qrow0 + qrow) * DD + nt * 16 + q15]);
        dot = fmaf(ov, qv, dot);
        o2 = fmaf(ov, ov, o2);
        q2 = fmaf(qv, qv, q2);
      }
#pragma unroll
      for (int off = 1; off < 16; off <<= 1) {
        dot += __shfl_xor(dot, off, 64);
        o2 += __shfl_xor(o2, off, 64);
        q2 += __shfl_xor(q2, off, 64);
      }
      total += dot / (sqrtf(o2 * q2) + dnq * EPSV);
    }
  }
  total += __shfl_xor(total, 16, 64);
  total += __shfl_xor(total, 32, 64);
  if (l == 0) atomicAdd(&out[b], invN * total);
}

// ---------------------------------------------------------------------------
extern "C" void kernel_launch(void* const* d_in, const int* in_sizes, int n_in,
                              void* d_out, int out_size, void* d_ws, size_t ws_size,
                              hipStream_t stream) {
  const float* text  = (const float*)d_in[0];
  const float* image = (const float*)d_in[1];
  const float* Wt    = (const float*)d_in[2];
  const float* bt    = (const float*)d_in[3];
  const float* Wi    = (const float*)d_in[4];
  const float* bi    = (const float*)d_in[5];
  float* out = (float*)d_out;

  constexpr size_t NE = (size_t)BB * NROW * DD;
  unsigned short* tf   = (unsigned short*)d_ws;  // bf16 row-major
  unsigned short* imf  = tf + NE;
  unsigned short* tft  = imf + NE;               // bf16 [b][d][row]
  unsigned short* imft = tft + NE;
  unsigned short* wtt  = imft + NE;              // Wt text  [256][320]
  unsigned short* wti  = wtt + (size_t)DD * 320; // Wt image [256][1024]

  hipMemsetAsync(out, 0, sizeof(float) * BB, stream);

  prep_w<<<dim3(320 / 32, 8), 256, 0, stream>>>(Wt, wtt, DT, 320);
  prep_w<<<dim3(1024 / 32, 8), 256, 0, stream>>>(Wi, wti, DI, 1024);

  proj_mfma<<<dim3((BB * NROW) / 128), 512, 0, stream>>>(text, wtt, bt, tf, tft, DT, 320);
  proj_mfma<<<dim3((BB * NROW) / 128), 512, 0, stream>>>(image, wti, bi, imf, imft, DI, 1024);

  cross_attn_mfma<<<dim3(NROW / 128, BB), 256, 0, stream>>>(
      tf, imf, imft, out, 1.0f / NROW);
  cross_attn_mfma<<<dim3(NROW / 128, BB), 256, 0, stream>>>(
      imf, tf, tft, out, 1.0f / NROW);
}